// Round 1
// baseline (1608.203 us; speedup 1.0000x reference)
//
#include <hip/hip_runtime.h>

// CRF forward (log-partition) + gold score, fused.
// B=4096, L=1024, T=32. Layout: half-wave (32 lanes) per sequence, lane = state.
// Core transform: logsumexp over prev -> exp-domain matvec with M = exp(trans),
// single per-step max m shared across all 'next' states.

#define BATCH 4096
#define LSEQ  1024
#define T     32
#define START 30
#define STOP  31
#define NEGV  (-10000.0f)

__global__ __launch_bounds__(256) void crf_fwd_kernel(
    const float* __restrict__ feats,   // [B, L, T]
    const float* __restrict__ trans,   // [T, T] (next, prev)
    const int*   __restrict__ tags,    // [B, L]
    float*       __restrict__ out)     // [B]
{
    __shared__ float trans_s[T * T];   // raw transitions for gold + finalization
    const int tid = threadIdx.x;
    for (int i = tid; i < T * T; i += 256) trans_s[i] = trans[i];
    __syncthreads();

    const int s   = tid & 31;          // state index (lane within half-wave)
    const int seq = tid >> 5;          // 0..7 within block
    const int b   = blockIdx.x * 8 + seq;

    // Per-lane row of M = exp(trans): Mrow[k] = exp(trans[next=s][prev=k]).
    // exp(-10000) underflows to exactly 0 -> structural constraints become exact zeros.
    float Mrow[T];
#pragma unroll
    for (int k = 0; k < T; ++k) Mrow[k] = __expf(trans[s * T + k]);

    const float* fb = feats + (size_t)b * (LSEQ * T);
    const int*   tb = tags  + (size_t)b * LSEQ;

    float fv = (s == START) ? 0.0f : NEGV;   // forward variable, lane = prev-state holder
    float gold_emit  = 0.0f;                 // per-lane, reduced at the end
    float gold_trans = 0.0f;                 // accumulated on lane 0 only
    int   prev_tag   = START;

    // 4-deep software prefetch of feats/tags (hides HBM latency at 2 waves/SIMD)
    const int PF = 4;
    float fbuf[4]; int tbuf[4];
#pragma unroll
    for (int i = 0; i < PF; ++i) { fbuf[i] = fb[i * T + s]; tbuf[i] = tb[i]; }

#pragma unroll 4
    for (int l = 0; l < LSEQ; ++l) {
        const int slot = l & (PF - 1);
        const float f  = fbuf[slot];
        const int  tag = tbuf[slot];
        if (l + PF < LSEQ) {
            fbuf[slot] = fb[(l + PF) * T + s];
            tbuf[slot] = tb[l + PF];
        }

        // m = max over the 32 states of this sequence (butterfly within half-wave)
        float m = fv;
#pragma unroll
        for (int d = 1; d < 32; d <<= 1) m = fmaxf(m, __shfl_xor(m, d, 32));

        const float E = __expf(fv - m);      // in [0,1]; exp(-inf - m) = 0

        // acc[next=s] = sum_prev E[prev] * M[s][prev]
        float acc = 0.0f;
#pragma unroll
        for (int k = 0; k < T; ++k)
            acc = fmaf(__shfl(E, k, 32), Mrow[k], acc);

        fv = m + __logf(acc) + f;            // log(0) = -inf for blocked states (START)

        // gold path score (fused): emission picked up by the lane holding state==tag
        if (s == tag) gold_emit += f;
        if (s == 0)   gold_trans += trans_s[tag * T + prev_tag];
        prev_tag = tag;
    }

    // alpha = logsumexp(fv + trans[STOP, :])
    float v = fv + trans_s[STOP * T + s];
    float m2 = v;
#pragma unroll
    for (int d = 1; d < 32; d <<= 1) m2 = fmaxf(m2, __shfl_xor(m2, d, 32));
    float e2 = __expf(v - m2);
#pragma unroll
    for (int d = 1; d < 32; d <<= 1) e2 += __shfl_xor(e2, d, 32);
    const float alpha = m2 + __logf(e2);

    // gold = sum(emit) + sum(trans) + trans[STOP, last_tag]
    float ge = gold_emit;
#pragma unroll
    for (int d = 1; d < 32; d <<= 1) ge += __shfl_xor(ge, d, 32);
    const float gold = ge + __shfl(gold_trans, 0, 32) + trans_s[STOP * T + prev_tag];

    if (s == 0) out[b] = alpha - gold;
}

extern "C" void kernel_launch(void* const* d_in, const int* in_sizes, int n_in,
                              void* d_out, int out_size, void* d_ws, size_t ws_size,
                              hipStream_t stream) {
    const float* feats = (const float*)d_in[0];
    const float* trans = (const float*)d_in[1];
    const int*   tags  = (const int*)d_in[2];
    float*       out   = (float*)d_out;

    // 8 sequences per 256-thread block (half-wave per sequence)
    const int blocks = BATCH / 8;   // 512
    crf_fwd_kernel<<<blocks, 256, 0, stream>>>(feats, trans, tags, out);
}

// Round 2
// 1236.184 us; speedup vs baseline: 1.3009x; 1.3009x over previous
//
#include <hip/hip_runtime.h>

// CRF forward (log-partition) + gold score, fused.
// B=4096, L=1024, T=32. Half-wave (32 lanes) per sequence, lane = state.
// Round-2 change: all per-step cross-lane shuffles (37 serialized ds_bpermute,
// ~2600 cyc/step) replaced by two wave-synchronous LDS roundtrips:
//   - m = max(fv[0], fv[START]) via ds_write + ds_read2 (any finite shift is
//     exact for logsumexp; fv[0] is provably within ~20 of the true max)
//   - E broadcast via ds_write + 8 independent ds_read_b128 (same-address
//     broadcast within half-wave; 2-way across half-waves = conflict-free)

#define BATCH 4096
#define LSEQ  1024
#define T     32
#define START 30
#define STOP  31
#define NEGV  (-10000.0f)

__global__ __launch_bounds__(256) void crf_fwd_kernel(
    const float* __restrict__ feats,   // [B, L, T]
    const float* __restrict__ trans,   // [T, T] (next, prev)
    const int*   __restrict__ tags,    // [B, L]
    float*       __restrict__ out)     // [B]
{
    __shared__ float trans_s[T * T];                 // raw transitions (gold + finalize)
    __shared__ __align__(16) float fv_s[8][T];       // per half-wave fv scratch
    __shared__ __align__(16) float e_s[8][T];        // per half-wave E scratch

    const int tid = threadIdx.x;
    for (int i = tid; i < T * T; i += 256) trans_s[i] = trans[i];
    __syncthreads();

    const int s  = tid & 31;           // state index (lane within half-wave)
    const int hw = tid >> 5;           // half-wave id 0..7 within block
    const int b  = blockIdx.x * 8 + hw;

    // Per-lane row of M = exp(trans). exp(-10000) == 0 -> structural zeros exact.
    float Mrow[T];
#pragma unroll
    for (int k = 0; k < T; ++k) Mrow[k] = __expf(trans_s[s * T + k]);

    const float* fb = feats + (size_t)b * (LSEQ * T);
    const int*   tb = tags  + (size_t)b * LSEQ;

    float fv = (s == START) ? 0.0f : NEGV;
    float gold_emit  = 0.0f;           // per-lane, reduced at end
    float gold_trans = 0.0f;           // uniform across half-wave (broadcast LDS read)
    int   prev_tag   = START;

    float* __restrict__ myfv = fv_s[hw];
    float* __restrict__ mye  = e_s[hw];

    // 4-deep software prefetch of feats/tags
    const int PF = 4;
    float fbuf[PF]; int tbuf[PF];
#pragma unroll
    for (int i = 0; i < PF; ++i) { fbuf[i] = fb[i * T + s]; tbuf[i] = tb[i]; }

#pragma unroll 4
    for (int l = 0; l < LSEQ; ++l) {
        const int slot = l & (PF - 1);
        const float f  = fbuf[slot];
        const int  tag = tbuf[slot];
        if (l + PF < LSEQ) {
            fbuf[slot] = fb[(l + PF) * T + s];
            tbuf[slot] = tb[l + PF];
        }

        // shift m: any finite value close to the max works (exact identity).
        myfv[s] = fv;
        __builtin_amdgcn_wave_barrier();
        const float m = fmaxf(myfv[0], myfv[START]);   // ds_read2, broadcast

        const float E = __expf(fv - m);                // exp(-inf - m) = 0
        mye[s] = E;
        __builtin_amdgcn_wave_barrier();

        // acc[next=s] = sum_prev E[prev] * M[s][prev]; 8x float4 broadcast reads,
        // 4-way split accumulators to break the FMA chain.
        float acc0 = 0.f, acc1 = 0.f, acc2 = 0.f, acc3 = 0.f;
        const float4* ev = (const float4*)mye;
#pragma unroll
        for (int k4 = 0; k4 < T / 4; ++k4) {
            const float4 e = ev[k4];
            acc0 = fmaf(e.x, Mrow[4 * k4 + 0], acc0);
            acc1 = fmaf(e.y, Mrow[4 * k4 + 1], acc1);
            acc2 = fmaf(e.z, Mrow[4 * k4 + 2], acc2);
            acc3 = fmaf(e.w, Mrow[4 * k4 + 3], acc3);
        }
        const float acc = (acc0 + acc1) + (acc2 + acc3);

        fv = m + __logf(acc) + f;      // log(0) = -inf for blocked START state

        // gold path score (fused)
        if (s == tag) gold_emit += f;
        gold_trans += trans_s[tag * T + prev_tag];     // broadcast read, uniform
        prev_tag = tag;
    }

    // alpha = logsumexp(fv + trans[STOP, :]) — one-time butterflies are fine here
    float v = fv + trans_s[STOP * T + s];
    float m2 = v;
#pragma unroll
    for (int d = 1; d < 32; d <<= 1) m2 = fmaxf(m2, __shfl_xor(m2, d, 32));
    float e2 = __expf(v - m2);
#pragma unroll
    for (int d = 1; d < 32; d <<= 1) e2 += __shfl_xor(e2, d, 32);
    const float alpha = m2 + __logf(e2);

    float ge = gold_emit;
#pragma unroll
    for (int d = 1; d < 32; d <<= 1) ge += __shfl_xor(ge, d, 32);
    const float gold = ge + gold_trans + trans_s[STOP * T + prev_tag];

    if (s == 0) out[b] = alpha - gold;
}

extern "C" void kernel_launch(void* const* d_in, const int* in_sizes, int n_in,
                              void* d_out, int out_size, void* d_ws, size_t ws_size,
                              hipStream_t stream) {
    const float* feats = (const float*)d_in[0];
    const float* trans = (const float*)d_in[1];
    const int*   tags  = (const int*)d_in[2];
    float*       out   = (float*)d_out;

    const int blocks = BATCH / 8;   // 8 sequences per 256-thread block
    crf_fwd_kernel<<<blocks, 256, 0, stream>>>(feats, trans, tags, out);
}

// Round 3
// 1207.776 us; speedup vs baseline: 1.3315x; 1.0235x over previous
//
#include <hip/hip_runtime.h>
#include <hip/hip_bf16.h>

// CRF forward + gold score via MFMA.
// B=4096, L=1024, T=32. One wave per 16 sequences; lane = (batch n=lane&15, q=lane>>4).
// Per step: acc[b,s] = sum_prev Mexp[s][prev] * E[prev,b] via 2x mfma_f32_16x16x32_bf16
// with ROW-PERMUTED A so that the D layout (lane holds states 8q..8q+7 for batch n)
// is exactly the B-fragment layout of the next step -> no cross-lane E movement.
// Shift update: delta = log(acc[b,0]) + feat[b,l,0] (1 log/batch, bpermute broadcast);
// E_new[s] = acc[s] * exp(feat[s] - delta).  E[b,0] == 1 always.

#define BATCH 4096
#define LSEQ  1024
#define T     32
#define START 30
#define STOP  31

typedef __attribute__((ext_vector_type(8))) short short8;
typedef __attribute__((ext_vector_type(4))) float f32x4;

static __device__ __forceinline__ short bf16b(float x) {
    union { __hip_bfloat16 h; short s; } u;
    u.h = __float2bfloat16(x);
    return u.s;
}

__global__ __launch_bounds__(64) void crf_fwd_mfma(
    const float* __restrict__ feats,   // [B, L, T]
    const float* __restrict__ trans,   // [T, T] (next, prev)
    const int*   __restrict__ tags,    // [B, L]
    float*       __restrict__ out)     // [B]
{
    __shared__ float trans_s[T * T];
    const int lane = threadIdx.x;      // 0..63
    for (int i = lane; i < T * T; i += 64) trans_s[i] = trans[i];
    __syncthreads();

    const int n = lane & 15;           // batch within the wave's group of 16
    const int q = lane >> 4;           // quadrant: owns states 8q..8q+7
    const int b = blockIdx.x * 16 + n;

    // A fragments (Mexp, row-permuted). A[m][k]: m = lane&15, k = 8q + j.
    // A1 row m -> state 8*(m>>2)+(m&3); A2 row m -> that +4. exp(-10000)==0 exact.
    short8 a1, a2;
    {
        const int s1 = 8 * (n >> 2) + (n & 3);
        const int s2 = s1 + 4;
#pragma unroll
        for (int j = 0; j < 8; ++j) {
            a1[j] = bf16b(__expf(trans_s[s1 * T + 8 * q + j]));
            a2[j] = bf16b(__expf(trans_s[s2 * T + 8 * q + j]));
        }
    }

    // B fragment: E[k = 8q+j][n]. Init fv: START=0, rest -1e4 -> E = one-hot(START).
    short8 bfrag;
#pragma unroll
    for (int j = 0; j < 8; ++j) bfrag[j] = 0;
    if (q == 3) bfrag[6] = bf16b(1.0f);          // state 30 = 8*3+6

    const f32x4* fp = (const f32x4*)(feats + (size_t)b * (LSEQ * T) + 8 * q);
    const int*   tb = tags + (size_t)b * LSEQ;

    // 8-deep register ring prefetch: 2 float4 (states 8q..8q+7) + tag per step
    f32x4 fr0[8], fr1[8];
    int   tbuf[8];
#pragma unroll
    for (int i = 0; i < 8; ++i) {
        fr0[i] = fp[i * 8];
        fr1[i] = fp[i * 8 + 1];
        tbuf[i] = tb[i];
    }

    float mAcc = 0.0f;        // running shift m_b = fv[b,0] (uniform across q)
    float gold_trans = 0.0f;  // uniform across q
    float gold_emit = 0.0f;   // per-lane partial, reduced at end
    int   prev_tag = START;
    float ev[8];              // fp32 E of the current step (kept for epilogue)

    const f32x4 zacc = {0.f, 0.f, 0.f, 0.f};

#define CRF_STEP(l, DO_PF)                                                     \
    {                                                                          \
        const int   slot = (l) & 7;                                            \
        const f32x4 f0   = fr0[slot];                                          \
        const f32x4 f1   = fr1[slot];                                          \
        const int   tag  = tbuf[slot];                                         \
        if (DO_PF) {                                                           \
            fr0[slot]  = fp[((l) + 8) * 8];                                    \
            fr1[slot]  = fp[((l) + 8) * 8 + 1];                                \
            tbuf[slot] = tb[(l) + 8];                                          \
        }                                                                      \
        f32x4 c1 = __builtin_amdgcn_mfma_f32_16x16x32_bf16(a1, bfrag, zacc, 0, 0, 0); \
        f32x4 c2 = __builtin_amdgcn_mfma_f32_16x16x32_bf16(a2, bfrag, zacc, 0, 0, 0); \
        const float dsrc  = __logf(c1[0]) + f0[0];  /* valid in q==0 (lane b) */ \
        const float delta = __shfl(dsrc, n, 64);                               \
        mAcc += delta;                                                         \
        _Pragma("unroll")                                                      \
        for (int r = 0; r < 4; ++r) {                                          \
            ev[r]     = c1[r] * __expf(f0[r] - delta);                         \
            ev[4 + r] = c2[r] * __expf(f1[r] - delta);                         \
        }                                                                      \
        _Pragma("unroll")                                                      \
        for (int j = 0; j < 8; ++j) bfrag[j] = bf16b(ev[j]);                   \
        /* gold: transitions (uniform) + emission (owned by lane q==tag>>3) */ \
        gold_trans += trans_s[tag * T + prev_tag];                             \
        {                                                                      \
            const f32x4 fs  = (tag & 4) ? f1 : f0;                             \
            const float p01 = (tag & 1) ? fs[1] : fs[0];                       \
            const float p23 = (tag & 1) ? fs[3] : fs[2];                       \
            const float pk  = (tag & 2) ? p23 : p01;                           \
            if ((tag >> 3) == q) gold_emit += pk;                              \
        }                                                                      \
        prev_tag = tag;                                                        \
    }

#pragma unroll 4
    for (int l = 0; l < LSEQ - 8; ++l) CRF_STEP(l, 1);
#pragma unroll
    for (int l = LSEQ - 8; l < LSEQ; ++l) CRF_STEP(l, 0);
#undef CRF_STEP

    // alpha = m + log(sum_s E[s] * Mexp[STOP][s])
    float s = 0.0f;
#pragma unroll
    for (int j = 0; j < 8; ++j)
        s += ev[j] * __expf(trans_s[STOP * T + 8 * q + j]);
    s += __shfl_xor(s, 16, 64);
    s += __shfl_xor(s, 32, 64);
    const float alpha = mAcc + __logf(s);

    float ge = gold_emit;
    ge += __shfl_xor(ge, 16, 64);
    ge += __shfl_xor(ge, 32, 64);
    const float gold = ge + gold_trans + trans_s[STOP * T + prev_tag];

    if (lane < 16) out[b] = alpha - gold;
}

extern "C" void kernel_launch(void* const* d_in, const int* in_sizes, int n_in,
                              void* d_out, int out_size, void* d_ws, size_t ws_size,
                              hipStream_t stream) {
    const float* feats = (const float*)d_in[0];
    const float* trans = (const float*)d_in[1];
    const int*   tags  = (const int*)d_in[2];
    float*       out   = (float*)d_out;

    // 16 sequences per 64-thread block -> 256 blocks = 1 wave per CU
    crf_fwd_mfma<<<BATCH / 16, 64, 0, stream>>>(feats, trans, tags, out);
}